// Round 3
// baseline (394.821 us; speedup 1.0000x reference)
//
#include <hip/hip_runtime.h>

// Problem constants: images (16,3,768,768) f32, h=w=48, N=2304,
// SIGMA_COLOR=0.1 -> exp(-50*cd), SIGMA_SPATIAL=5 -> exp(-0.02*sd), RADIUS=8.
#define BATCH 16
#define CH    3
#define HIN   768
#define WIN   768
#define HS    48
#define WS    48
#define NPIX  (HS * WS)          // 2304
#define QPR   (NPIX / 4)         // 576 float4 quads per output row
#define ROWS_PB 4                // output rows handled per block

typedef float f32x4 __attribute__((ext_vector_type(4)));  // native vec for NT stores

// Kernel 1: bilinear downsample 768->48 (half-pixel centers, scale 16).
// Sample coord 16*i + 7.5 -> exact 2x2 average of pixels {16i+7, 16i+8}.
__global__ void downsample_kernel(const float* __restrict__ img,
                                  f32x4* __restrict__ feats) {
    int idx = blockIdx.x * blockDim.x + threadIdx.x;   // over BATCH*NPIX = 36864
    if (idx >= BATCH * NPIX) return;
    int b = idx / NPIX;
    int n = idx - b * NPIX;
    int y = n / WS;
    int x = n - y * WS;
    int iy = 16 * y + 7;
    int ix = 16 * x + 7;
    const float* base = img + (size_t)b * CH * HIN * WIN;
    float f[3];
#pragma unroll
    for (int c = 0; c < 3; ++c) {
        const float* p = base + (size_t)c * HIN * WIN;
        const float* r0 = p + (size_t)iy * WIN + ix;
        const float* r1 = r0 + WIN;
        f[c] = 0.25f * (r0[0] + r0[1] + r1[0] + r1[1]);
    }
    f32x4 v = {f[0], f[1], f[2], 0.0f};
    feats[idx] = v;
}

// Kernel 2: out[b][i][j] = mask(|dy|<=8,|dx|<=8) * exp(-50*||fi-fj||^2 - 0.02*(dy^2+dx^2))
// Block owns ROWS_PB complete (b,i) rows: i/b decode is per-block scalar,
// threads issue ~9 independent nontemporal float4 stores each (ILP for the
// store stream), no per-thread wide integer divides. 48%4==0 -> a quad never
// crosses a j-grid-row, so one dy test covers the quad.
__global__ __launch_bounds__(256) void affinity_kernel(const f32x4* __restrict__ feats,
                                                       f32x4* __restrict__ out) {
    const int tid = threadIdx.x;                 // 0..255
    const int b   = blockIdx.y;                  // 0..15
    const int i0  = blockIdx.x * ROWS_PB;        // 0..2300 step 4
    const f32x4* __restrict__ frow = feats + b * NPIX;

#pragma unroll
    for (int ii = 0; ii < ROWS_PB; ++ii) {
        const int i  = i0 + ii;
        const int yi = i / WS;                   // block-uniform scalar
        const int xi = i - yi * WS;
        const f32x4 fi = frow[i];                // broadcast load (L1/L2 hit)
        f32x4* __restrict__ orow = out + (size_t)(b * NPIX + i) * QPR;

        // 576 quads with 256 threads: q = tid, tid+256, tid+512 (tid<64)
#pragma unroll
        for (int qi = 0; qi < 3; ++qi) {
            const int q = tid + qi * 256;
            if (qi < 2 || q < QPR) {
                const int yj  = q / 12;          // 12 quads per j-grid-row
                const int xj0 = (q - yj * 12) * 4;
                const int dy  = yi - yj;
                f32x4 r = {0.f, 0.f, 0.f, 0.f};
                if ((unsigned)(dy + 8) <= 16u) {
                    const float sdy = (float)(dy * dy);
#pragma unroll
                    for (int k = 0; k < 4; ++k) {
                        const int dx = xi - (xj0 + k);
                        const f32x4 fj = frow[4 * q + k];
                        const float d0 = fi.x - fj.x;
                        const float d1 = fi.y - fj.y;
                        const float d2 = fi.z - fj.z;
                        const float cd = d0 * d0 + d1 * d1 + d2 * d2;
                        const float sd = sdy + (float)(dx * dx);
                        const float e  = __expf(-50.0f * cd - 0.02f * sd);
                        r[k] = ((unsigned)(dx + 8) <= 16u) ? e : 0.0f;
                    }
                }
                __builtin_nontemporal_store(r, &orow[q]);
            }
        }
    }
}

extern "C" void kernel_launch(void* const* d_in, const int* in_sizes, int n_in,
                              void* d_out, int out_size, void* d_ws, size_t ws_size,
                              hipStream_t stream) {
    const float* img = (const float*)d_in[0];
    f32x4* feats = (f32x4*)d_ws;                   // 16*2304*16 B = 589,824 B
    f32x4* out   = (f32x4*)d_out;

    {
        int threads = BATCH * NPIX;                // 36,864
        int block = 256;
        int grid = (threads + block - 1) / block;  // 144
        downsample_kernel<<<grid, block, 0, stream>>>(img, feats);
    }
    {
        dim3 grid(NPIX / ROWS_PB, BATCH);          // (576, 16) blocks
        affinity_kernel<<<grid, 256, 0, stream>>>(feats, out);
    }
}

// Round 4
// 391.122 us; speedup vs baseline: 1.0095x; 1.0095x over previous
//
#include <hip/hip_runtime.h>

// Problem constants: images (16,3,768,768) f32, h=w=48, N=2304,
// SIGMA_COLOR=0.1 -> exp(-50*cd), SIGMA_SPATIAL=5 -> exp(-0.02*sd), RADIUS=8.
#define BATCH 16
#define CH    3
#define HIN   768
#define WIN   768
#define HS    48
#define WS    48
#define NPIX  (HS * WS)          // 2304
#define QPR   (NPIX / 4)         // 576 float4 quads per output row
#define ROWS_PB 4                // output rows per block; 4|48 -> all share one yi

typedef float f32x4 __attribute__((ext_vector_type(4)));

// Kernel 1: bilinear downsample 768->48 (half-pixel centers, scale 16).
// Sample coord 16*i + 7.5 -> exact 2x2 average of pixels {16i+7, 16i+8}.
__global__ void downsample_kernel(const float* __restrict__ img,
                                  f32x4* __restrict__ feats) {
    int idx = blockIdx.x * blockDim.x + threadIdx.x;   // over BATCH*NPIX = 36864
    if (idx >= BATCH * NPIX) return;
    int b = idx / NPIX;
    int n = idx - b * NPIX;
    int y = n / WS;
    int x = n - y * WS;
    int iy = 16 * y + 7;
    int ix = 16 * x + 7;
    const float* base = img + (size_t)b * CH * HIN * WIN;
    float f[3];
#pragma unroll
    for (int c = 0; c < 3; ++c) {
        const float* p = base + (size_t)c * HIN * WIN;
        const float* r0 = p + (size_t)iy * WIN + ix;
        const float* r1 = r0 + WIN;
        f[c] = 0.25f * (r0[0] + r0[1] + r1[0] + r1[1]);
    }
    f32x4 v = {f[0], f[1], f[2], 0.0f};
    feats[idx] = v;
}

// Kernel 2: block owns 4 output rows sharing one yi. The nonzero j-band
// [12*(yi-8), 12*(yi+9)) is block-uniform, so:
//   Phase Z: memset-style dense zero stores over the complement (no compute).
//   Phase C: band quads only (<=204/row); dy-mask free by construction
//            (band = whole yj rows); per-quad metadata + fj loads hoisted
//            out of the 4-row loop.
__global__ __launch_bounds__(256) void affinity_kernel(const f32x4* __restrict__ feats,
                                                       f32x4* __restrict__ out) {
    const int tid = threadIdx.x;                 // 0..255
    const int b   = blockIdx.y;                  // 0..15
    const int i0  = blockIdx.x * ROWS_PB;        // 0..2300 step 4
    const int yi  = i0 / WS;                     // block-uniform (4 | 48)
    const int xi0 = i0 - yi * WS;

    const int ylo   = (yi - 8 > 0) ? yi - 8 : 0;
    const int yhi   = (yi + 8 < HS - 1) ? yi + 8 : HS - 1;
    const int qlo   = 12 * ylo;                  // band start (quad units)
    const int qhi   = 12 * (yhi + 1);            // band end
    const int bandw = qhi - qlo;                 // 108..204  (< 256)
    const int nz    = QPR - bandw;               // 372..468  (< 512)

    const f32x4* __restrict__ frow  = feats + b * NPIX;
    f32x4* __restrict__       obase = out + (size_t)(b * NPIX + i0) * QPR;

    // --- band metadata + fj loads (issue early, reused across 4 rows) ---
    const bool inband = tid < bandw;
    int   q = 0, xj[4];
    float sdy = 0.0f;
    f32x4 fj[4];
    if (inband) {
        q = qlo + tid;
        const int yj  = q / 12;                  // magic-mul, once per quad
        const int dy  = yi - yj;                 // |dy| <= 8 by construction
        sdy = (float)(dy * dy);
        const int xj0 = (q - yj * 12) * 4;
#pragma unroll
        for (int k = 0; k < 4; ++k) {
            xj[k] = xj0 + k;
            fj[k] = frow[4 * q + k];
        }
    }

    // --- Phase Z: dense zero stores, no value compute ---
    const f32x4 z = {0.f, 0.f, 0.f, 0.f};
#pragma unroll
    for (int iter = 0; iter < 2; ++iter) {
        const int t2 = tid + 256 * iter;
        if (t2 < nz) {
            const int zq = (t2 < qlo) ? t2 : t2 + bandw;
#pragma unroll
            for (int ii = 0; ii < ROWS_PB; ++ii)
                obase[(size_t)ii * QPR + zq] = z;
        }
    }

    // --- Phase C: band compute + stores ---
    if (inband) {
#pragma unroll
        for (int ii = 0; ii < ROWS_PB; ++ii) {
            const f32x4 fi = frow[i0 + ii];      // wave-uniform -> scalar load
            const int   xi = xi0 + ii;
            f32x4 r;
#pragma unroll
            for (int k = 0; k < 4; ++k) {
                const int   dx = xi - xj[k];
                const float d0 = fi.x - fj[k].x;
                const float d1 = fi.y - fj[k].y;
                const float d2 = fi.z - fj[k].z;
                const float cd = d0 * d0 + d1 * d1 + d2 * d2;
                const float sd = sdy + (float)(dx * dx);
                const float e  = __expf(-50.0f * cd - 0.02f * sd);
                r[k] = ((unsigned)(dx + 8) <= 16u) ? e : 0.0f;
            }
            obase[(size_t)ii * QPR + q] = r;
        }
    }
}

extern "C" void kernel_launch(void* const* d_in, const int* in_sizes, int n_in,
                              void* d_out, int out_size, void* d_ws, size_t ws_size,
                              hipStream_t stream) {
    const float* img = (const float*)d_in[0];
    f32x4* feats = (f32x4*)d_ws;                   // 16*2304*16 B = 589,824 B
    f32x4* out   = (f32x4*)d_out;

    {
        int threads = BATCH * NPIX;                // 36,864
        int block = 256;
        int grid = (threads + block - 1) / block;  // 144
        downsample_kernel<<<grid, block, 0, stream>>>(img, feats);
    }
    {
        dim3 grid(NPIX / ROWS_PB, BATCH);          // (576, 16) blocks
        affinity_kernel<<<grid, 256, 0, stream>>>(feats, out);
    }
}